// Round 11
// baseline (108.496 us; speedup 1.0000x reference)
//
#include <hip/hip_runtime.h>

// Chamfer distance via bf16 MFMA with hi/lo split (fp32-grade precision).
// d(p,q) = ||p||^2 + ||q||^2 - 2 p.q.
// A row (target): [uh x3, uh x3, ul x3, ul x3, wh wm wl, 0], u=-2t, w=||t||^2
// B col (query):  [qh x3, ql x3, qh x3, ql x3, 1 1 1, 0]
// => D = -2 t.q + ||t||^2 + O(1e-5); query ||q||^2 added after the min.
//
// R11 pipe-balance config (first one MFMA-bound on ALL pipes):
//  - 64-query waves, 2 MFMA per ds_read_b128  (DS 96 < MFMA 258 cyc/CU-slot)
//  - min3 accumulation macc=min3(macc,d0,d1)  (VALU 16 inst/tile, half of R10)
//  - z-split x2 over targets -> 2048 blocks, SLICE=512 (2x16KiB dbuf) ->
//    3 blocks/CU at LB(256,3) = 3 waves/SIMD latency hiding
//  - async global_load_lds staging (R10-proven, pre-swizzled source)
//  - atomicMin minbuf + small reduce kernel (R1-R4-proven path)
// Spill history: R8 full-unroll (3.4GB scratch), R9 rg[] staging (80MB).
// Keep unroll 2 + zero-VGPR staging; check WRITE_SIZE stays ~1MB.

typedef short bf16x8 __attribute__((ext_vector_type(8)));
typedef float f32x16 __attribute__((ext_vector_type(16)));

#define B_SZ   8
#define NPTS   8192
#define TOTAL  (B_SZ * NPTS)     // 65536
#define BLOCK  256
#define QB     256               // queries per nn block (4 waves x 64)
#define ZSPLIT 2
#define HALF   (NPTS / ZSPLIT)   // 4096 targets per z-half
#define SLICE  512               // targets per LDS stage
#define NSTAGE (HALF / SLICE)    // 8
#define TILES  (SLICE / 32)      // 16
#define BUFB   (SLICE * 32)      // 16384 bytes per LDS buffer
#define RED_GRID 64

// round-to-nearest bf16 (half-up via +0x8000 carry), return remainder
__device__ __forceinline__ unsigned short bf16rn(float f, float* rem) {
    unsigned u = __float_as_uint(f);
    unsigned h = (u + 0x8000u) & 0xFFFF0000u;
    *rem = f - __uint_as_float(h);
    return (unsigned short)(h >> 16);
}

// One thread per point; blockIdx.y: 0 = gt, 1 = pred.  (round-4/6 exact)
__global__ __launch_bounds__(BLOCK) void chamfer_prep_mfma(
    const float* __restrict__ gt, const float* __restrict__ pred,
    uint4* __restrict__ TgA, uint4* __restrict__ TgB, float* __restrict__ Wg,
    uint4* __restrict__ TpA, uint4* __restrict__ TpB, float* __restrict__ Wp)
{
    int i = blockIdx.x * BLOCK + threadIdx.x;
    const float* src = blockIdx.y ? pred : gt;
    uint4* TA = blockIdx.y ? TpA : TgA;
    uint4* TB = blockIdx.y ? TpB : TgB;
    float* W  = blockIdx.y ? Wp  : Wg;

    float x = src[3 * (size_t)i + 0];
    float y = src[3 * (size_t)i + 1];
    float z = src[3 * (size_t)i + 2];
    float w = fmaf(x, x, fmaf(y, y, z * z));
    W[i] = w;

    float ux = -2.f * x, uy = -2.f * y, uz = -2.f * z;
    float rx, ry, rz, dx, dy, dz, rw1, rw2, rw3;
    unsigned short uhx = bf16rn(ux, &rx), uhy = bf16rn(uy, &ry), uhz = bf16rn(uz, &rz);
    unsigned short ulx = bf16rn(rx, &dx), uly = bf16rn(ry, &dy), ulz = bf16rn(rz, &dz);
    unsigned short wh = bf16rn(w, &rw1), wm = bf16rn(rw1, &rw2), wl = bf16rn(rw2, &rw3);
    union { unsigned short s[16]; uint4 v[2]; } A;
    A.s[0] = uhx; A.s[1] = uhy; A.s[2]  = uhz;
    A.s[3] = uhx; A.s[4] = uhy; A.s[5]  = uhz;
    A.s[6] = ulx; A.s[7] = uly; A.s[8]  = ulz;
    A.s[9] = ulx; A.s[10] = uly; A.s[11] = ulz;
    A.s[12] = wh; A.s[13] = wm; A.s[14] = wl; A.s[15] = 0;
    TA[2 * (size_t)i]     = A.v[0];
    TA[2 * (size_t)i + 1] = A.v[1];

    float sx, sy, sz, ex, ey, ez;
    unsigned short qhx = bf16rn(x, &sx), qhy = bf16rn(y, &sy), qhz = bf16rn(z, &sz);
    unsigned short qlx = bf16rn(sx, &ex), qly = bf16rn(sy, &ey), qlz = bf16rn(sz, &ez);
    union { unsigned short s[16]; uint4 v[2]; } Bb;
    Bb.s[0] = qhx; Bb.s[1] = qhy; Bb.s[2]  = qhz;
    Bb.s[3] = qlx; Bb.s[4] = qly; Bb.s[5]  = qlz;
    Bb.s[6] = qhx; Bb.s[7] = qhy; Bb.s[8]  = qhz;
    Bb.s[9] = qlx; Bb.s[10] = qly; Bb.s[11] = qlz;
    Bb.s[12] = 0x3F80; Bb.s[13] = 0x3F80; Bb.s[14] = 0x3F80; Bb.s[15] = 0;
    TB[2 * (size_t)i]     = Bb.v[0];
    TB[2 * (size_t)i + 1] = Bb.v[1];
}

// async 16B global->LDS (direct-to-LDS DMA, no VGPR round-trip; R10-proven)
__device__ __forceinline__ void gload_lds16(const void* g, void* l) {
    __builtin_amdgcn_global_load_lds(
        (const __attribute__((address_space(1))) unsigned int*)g,
        (__attribute__((address_space(3))) unsigned int*)l, 16, 0, 0);
}

// macc = min(macc, d0, d1) elementwise: 16 min3-fusable ops, depth 1
__device__ __forceinline__ f32x16 min3x16(f32x16 m, f32x16 d0, f32x16 d1) {
#pragma unroll
    for (int j = 0; j < 16; ++j) m[j] = fminf(fminf(m[j], d0[j]), d1[j]);
    return m;
}

// final 16 -> 1 tree (min3-fusable), once per kernel
__device__ __forceinline__ float mintree(f32x16 m) {
    float r0 = fminf(fminf(m[0], m[1]), m[2]);
    float r1 = fminf(fminf(m[3], m[4]), m[5]);
    float r2 = fminf(fminf(m[6], m[7]), m[8]);
    float r3 = fminf(fminf(m[9], m[10]), m[11]);
    float r4 = fminf(fminf(m[12], m[13]), m[14]);
    float s0 = fminf(fminf(r0, r1), r2);
    float s1 = fminf(fminf(r3, r4), m[15]);
    return fminf(s0, s1);
}

// grid (32 qb, 8 b, 4 = dir*2+zs), 256 threads / 4 waves, 3 blocks/CU.
// Wave w: queries qb*256 + w*64 .. +63 (two 32-col B-sets); this block
// covers targets [zs*HALF, zs*HALF+HALF) in 8 double-buffered stages.
__global__ __launch_bounds__(BLOCK, 3) void chamfer_nn_mfma(
    const uint4* __restrict__ TgA, const uint4* __restrict__ TpB,
    const float* __restrict__ Wp, unsigned* __restrict__ minP,
    const uint4* __restrict__ TpA, const uint4* __restrict__ TgB,
    const float* __restrict__ Wg, unsigned* __restrict__ minG)
{
    __shared__ uint4 tileU[2 * SLICE * 2];   // 2 x 16 KiB A-form buffers
    char* tileC = (char*)tileU;

    const int qb = blockIdx.x, b = blockIdx.y;
    const int dir = blockIdx.z >> 1, zs = blockIdx.z & 1;
    const int t = threadIdx.x, lane = t & 63, wid = t >> 6;
    const int col = lane & 31, hi = lane >> 5;

    const uint4* TA = dir ? TpA : TgA;
    const uint4* TB = dir ? TgB : TpB;
    const float* WQ = dir ? Wg  : Wp;
    unsigned*  minb = dir ? minG : minP;

    // B fragments (round-4/6 exact addressing)
    const int qblk = qb * QB + wid * 64;
    const char* TBc = (const char*)(TB + ((size_t)b * NPTS + qblk) * 2);
    bf16x8 bq0 = *(const bf16x8*)(TBc + (size_t)col * 32 + hi * 16);
    bf16x8 bq1 = *(const bf16x8*)(TBc + (size_t)(col + 32) * 32 + hi * 16);

    f32x16 zacc;
#pragma unroll
    for (int j = 0; j < 16; ++j) zacc[j] = 0.f;
    f32x16 macc0 = zacc + 3.0e38f;
    f32x16 macc1 = macc0;
    // swizzled A-frag READ base (HW-proven since R4); per-tile imm tt*1024
    const int abase = (col * 32 + hi * 16) ^ (((col >> 2) & 7) << 4);

    // staging (R10-proven scheme, SLICE=512): 1024 granules/stage, wave wid
    // owns chunks (wid*4+it), it<4; LINEAR LDS dest + XOR-pre-swizzled source
    // (g -> g^((g>>3)&7) involution within each 64-granule chunk).
    const uint4* TAb = TA + ((size_t)b * NPTS + (size_t)zs * HALF) * 2;
    const int swzlane = lane ^ (lane >> 3);
    const uint4* gsrc0 = TAb + wid * 256 + swzlane;
    char* ldst0 = tileC + wid * 4096;

    // prologue: stage 0 into buf0 (async; drained by barrier's vmcnt)
#pragma unroll
    for (int it = 0; it < 4; ++it)
        gload_lds16(gsrc0 + it * 64, ldst0 + it * 1024);
    __syncthreads();

    for (int st = 0; st < NSTAGE; ++st) {
        const int cur = (st & 1) * BUFB;
        if (st + 1 < NSTAGE) {               // issue next stage EARLY (async)
            const uint4* gs = gsrc0 + (size_t)(st + 1) * (SLICE * 2);
            char* ld = ldst0 + (cur ^ BUFB);
#pragma unroll
            for (int it = 0; it < 4; ++it)
                gload_lds16(gs + it * 64, ld + it * 1024);
        }

        const char* tb = tileC + cur + abase;
        bf16x8 a_cur = *(const bf16x8*)(tb);
#pragma unroll 2
        for (int tt = 0; tt < TILES - 1; ++tt) {
            bf16x8 a_nxt = *(const bf16x8*)(tb + (tt + 1) * 1024);
            f32x16 d0 = __builtin_amdgcn_mfma_f32_32x32x16_bf16(a_cur, bq0, zacc, 0, 0, 0);
            f32x16 d1 = __builtin_amdgcn_mfma_f32_32x32x16_bf16(a_cur, bq1, zacc, 0, 0, 0);
            macc0 = min3x16(macc0, d0, zacc + 3.0e38f);   // see note below
            macc1 = min3x16(macc1, d1, zacc + 3.0e38f);
            a_cur = a_nxt;
        }
        f32x16 d0 = __builtin_amdgcn_mfma_f32_32x32x16_bf16(a_cur, bq0, zacc, 0, 0, 0);
        f32x16 d1 = __builtin_amdgcn_mfma_f32_32x32x16_bf16(a_cur, bq1, zacc, 0, 0, 0);
        macc0 = min3x16(macc0, d0, zacc + 3.0e38f);
        macc1 = min3x16(macc1, d1, zacc + 3.0e38f);

        __syncthreads();                     // one barrier/stage (R8/R10 scheme)
    }

    // epilogue: 16->1 trees, combine row-halves, add ||q||^2, atomicMin
    float m0 = mintree(macc0);
    float m1 = mintree(macc1);
    m0 = fminf(m0, __shfl_xor(m0, 32));
    m1 = fminf(m1, __shfl_xor(m1, 32));
    // thread t <-> query qb*QB + t (R6-proven mapping)
    int qi = (int)((size_t)b * NPTS) + qb * QB + t;
    float wq = WQ[qi];
    float d = fmaxf((lane < 32 ? m0 : m1) + wq, 0.0f);
    atomicMin(&minb[qi], __float_as_uint(d));
}
// NOTE on min3x16 3rd arg: passing +BIG keeps the helper a 2-input min after
// constant-fold (fminf(x,BIG)=x), so codegen is macc=min(macc,d) per element,
// 16 v_min per MFMA pair when the compiler folds, 16 v_min3 otherwise — both
// are half of R10's 32 fmin. Value-identical either way.

// out += sum(a)*s + sum(b)*s  (multi-block; out zero-initialized)
__global__ __launch_bounds__(BLOCK) void chamfer_reduce(
    const float* __restrict__ a, const float* __restrict__ b,
    float* __restrict__ out, float sc)
{
    __shared__ float part[BLOCK / 64];
    float s = 0.f;
    int tid = blockIdx.x * BLOCK + threadIdx.x;
    int stride = gridDim.x * BLOCK;
    const float4* a4 = (const float4*)a;
    const float4* b4 = (const float4*)b;
    for (int i = tid; i < TOTAL / 4; i += stride) {
        float4 va = a4[i], vb = b4[i];
        s += (va.x + va.y + va.z + va.w) + (vb.x + vb.y + vb.z + vb.w);
    }
    s *= sc;
    for (int o = 32; o > 0; o >>= 1) s += __shfl_down(s, o, 64);
    int w = threadIdx.x >> 6;
    if ((threadIdx.x & 63) == 0) part[w] = s;
    __syncthreads();
    if (threadIdx.x == 0) {
        float tot = 0.f;
#pragma unroll
        for (int i = 0; i < BLOCK / 64; ++i) tot += part[i];
        atomicAdd(out, tot);
    }
}

extern "C" void kernel_launch(void* const* d_in, const int* in_sizes, int n_in,
                              void* d_out, int out_size, void* d_ws, size_t ws_size,
                              hipStream_t stream) {
    const float* pred = (const float*)d_in[0];   // [B, N, 3]
    const float* gt   = (const float*)d_in[1];   // [B, M, 3]
    float* out = (float*)d_out;

    // ws layout: TgA, TpA, TgB, TpB (32B/point), Wg, Wp, minP, minG
    char* ws = (char*)d_ws;
    uint4* TgA = (uint4*)(ws);
    uint4* TpA = (uint4*)(ws + (size_t)TOTAL * 32);
    uint4* TgB = (uint4*)(ws + (size_t)TOTAL * 64);
    uint4* TpB = (uint4*)(ws + (size_t)TOTAL * 96);
    float* Wg  = (float*)(ws + (size_t)TOTAL * 128);
    float* Wp  = (float*)(ws + (size_t)TOTAL * 132);
    unsigned* minP = (unsigned*)(ws + (size_t)TOTAL * 136);
    unsigned* minG = (unsigned*)(ws + (size_t)TOTAL * 140);

    hipMemsetAsync(minP, 0x7f, (size_t)TOTAL * 8, stream);  // minP+minG ~3.39e38
    hipMemsetAsync(out, 0, sizeof(float), stream);

    chamfer_prep_mfma<<<dim3(TOTAL / BLOCK, 2), BLOCK, 0, stream>>>(
        gt, pred, TgA, TgB, Wg, TpA, TpB, Wp);

    chamfer_nn_mfma<<<dim3(NPTS / QB, B_SZ, 2 * ZSPLIT), BLOCK, 0, stream>>>(
        TgA, TpB, Wp, minP, TpA, TgB, Wg, minG);

    chamfer_reduce<<<RED_GRID, BLOCK, 0, stream>>>(
        (const float*)minP, (const float*)minG, out, 1.0f / (float)TOTAL);
}

// Round 12
// 100.233 us; speedup vs baseline: 1.0824x; 1.0824x over previous
//
#include <hip/hip_runtime.h>

// Chamfer distance via bf16 MFMA with hi/lo split (fp32-grade precision).
// d(p,q) = ||p||^2 + ||q||^2 - 2 p.q.
// A row (target): [uh x3, uh x3, ul x3, ul x3, wh wm wl, 0], u=-2t, w=||t||^2
// B col (query):  [qh x3, ql x3, qh x3, ql x3, 1 1 1, 0]
// => D = -2 t.q + ||t||^2 + O(1e-5); query ||q||^2 added after the min.
//
// R12: make MFMA the strictly-dominant pipe.
//  - pair tiles: per iter {2 ds_read_b128, 4 MFMA, 2x min3x16} ->
//    v_min3_f32 retires TWO distances per op: VALU 64 cyc vs MFMA 129 /SIMD
//    (R11 bug: fminf(x,BIG) is NOT foldable (NaN semantics) -> 2x VALU)
//  - z-split x2, SLICE=512 (2x16KiB dbuf), LB(256,3) -> 3 waves/SIMD
//  - async global_load_lds staging (R10-proven), atomicMin + reduce (R1-proven)
// Spill history: R8 full-unroll (3.4GB scratch), R9 rg[] (80MB). unroll 1,
// zero-VGPR staging; check WRITE_SIZE ~1MB.

typedef short bf16x8 __attribute__((ext_vector_type(8)));
typedef float f32x16 __attribute__((ext_vector_type(16)));

#define B_SZ   8
#define NPTS   8192
#define TOTAL  (B_SZ * NPTS)     // 65536
#define BLOCK  256
#define QB     256               // queries per nn block (4 waves x 64)
#define ZSPLIT 2
#define HALF   (NPTS / ZSPLIT)   // 4096 targets per z-half
#define SLICE  512               // targets per LDS stage
#define NSTAGE (HALF / SLICE)    // 8
#define TILES  (SLICE / 32)      // 16
#define BUFB   (SLICE * 32)      // 16384 bytes per LDS buffer
#define RED_GRID 64

// round-to-nearest bf16 (half-up via +0x8000 carry), return remainder
__device__ __forceinline__ unsigned short bf16rn(float f, float* rem) {
    unsigned u = __float_as_uint(f);
    unsigned h = (u + 0x8000u) & 0xFFFF0000u;
    *rem = f - __uint_as_float(h);
    return (unsigned short)(h >> 16);
}

// One thread per point; blockIdx.y: 0 = gt, 1 = pred.  (round-4/6 exact)
__global__ __launch_bounds__(BLOCK) void chamfer_prep_mfma(
    const float* __restrict__ gt, const float* __restrict__ pred,
    uint4* __restrict__ TgA, uint4* __restrict__ TgB, float* __restrict__ Wg,
    uint4* __restrict__ TpA, uint4* __restrict__ TpB, float* __restrict__ Wp)
{
    int i = blockIdx.x * BLOCK + threadIdx.x;
    const float* src = blockIdx.y ? pred : gt;
    uint4* TA = blockIdx.y ? TpA : TgA;
    uint4* TB = blockIdx.y ? TpB : TgB;
    float* W  = blockIdx.y ? Wp  : Wg;

    float x = src[3 * (size_t)i + 0];
    float y = src[3 * (size_t)i + 1];
    float z = src[3 * (size_t)i + 2];
    float w = fmaf(x, x, fmaf(y, y, z * z));
    W[i] = w;

    float ux = -2.f * x, uy = -2.f * y, uz = -2.f * z;
    float rx, ry, rz, dx, dy, dz, rw1, rw2, rw3;
    unsigned short uhx = bf16rn(ux, &rx), uhy = bf16rn(uy, &ry), uhz = bf16rn(uz, &rz);
    unsigned short ulx = bf16rn(rx, &dx), uly = bf16rn(ry, &dy), ulz = bf16rn(rz, &dz);
    unsigned short wh = bf16rn(w, &rw1), wm = bf16rn(rw1, &rw2), wl = bf16rn(rw2, &rw3);
    union { unsigned short s[16]; uint4 v[2]; } A;
    A.s[0] = uhx; A.s[1] = uhy; A.s[2]  = uhz;
    A.s[3] = uhx; A.s[4] = uhy; A.s[5]  = uhz;
    A.s[6] = ulx; A.s[7] = uly; A.s[8]  = ulz;
    A.s[9] = ulx; A.s[10] = uly; A.s[11] = ulz;
    A.s[12] = wh; A.s[13] = wm; A.s[14] = wl; A.s[15] = 0;
    TA[2 * (size_t)i]     = A.v[0];
    TA[2 * (size_t)i + 1] = A.v[1];

    float sx, sy, sz, ex, ey, ez;
    unsigned short qhx = bf16rn(x, &sx), qhy = bf16rn(y, &sy), qhz = bf16rn(z, &sz);
    unsigned short qlx = bf16rn(sx, &ex), qly = bf16rn(sy, &ey), qlz = bf16rn(sz, &ez);
    union { unsigned short s[16]; uint4 v[2]; } Bb;
    Bb.s[0] = qhx; Bb.s[1] = qhy; Bb.s[2]  = qhz;
    Bb.s[3] = qlx; Bb.s[4] = qly; Bb.s[5]  = qlz;
    Bb.s[6] = qhx; Bb.s[7] = qhy; Bb.s[8]  = qhz;
    Bb.s[9] = qlx; Bb.s[10] = qly; Bb.s[11] = qlz;
    Bb.s[12] = 0x3F80; Bb.s[13] = 0x3F80; Bb.s[14] = 0x3F80; Bb.s[15] = 0;
    TB[2 * (size_t)i]     = Bb.v[0];
    TB[2 * (size_t)i + 1] = Bb.v[1];
}

// async 16B global->LDS (direct-to-LDS DMA, no VGPR round-trip; R10-proven)
__device__ __forceinline__ void gload_lds16(const void* g, void* l) {
    __builtin_amdgcn_global_load_lds(
        (const __attribute__((address_space(1))) unsigned int*)g,
        (__attribute__((address_space(3))) unsigned int*)l, 16, 0, 0);
}

// macc = min(macc, a, b) elementwise: 16 v_min3_f32 when fused, depth 1
__device__ __forceinline__ f32x16 min3x16(f32x16 m, f32x16 a, f32x16 b) {
#pragma unroll
    for (int j = 0; j < 16; ++j) m[j] = fminf(fminf(m[j], a[j]), b[j]);
    return m;
}

// final 16 -> 1 tree (min3-fusable), once per kernel
__device__ __forceinline__ float mintree(f32x16 m) {
    float r0 = fminf(fminf(m[0], m[1]), m[2]);
    float r1 = fminf(fminf(m[3], m[4]), m[5]);
    float r2 = fminf(fminf(m[6], m[7]), m[8]);
    float r3 = fminf(fminf(m[9], m[10]), m[11]);
    float r4 = fminf(fminf(m[12], m[13]), m[14]);
    float s0 = fminf(fminf(r0, r1), r2);
    float s1 = fminf(fminf(r3, r4), m[15]);
    return fminf(s0, s1);
}

// grid (32 qb, 8 b, 4 = dir*2+zs), 256 threads / 4 waves, 3 waves/SIMD.
// Wave w: queries qb*256 + w*64 .. +63 (two 32-col B-sets); block covers
// targets [zs*HALF, (zs+1)*HALF) in 8 double-buffered stages.
__global__ __launch_bounds__(BLOCK, 3) void chamfer_nn_mfma(
    const uint4* __restrict__ TgA, const uint4* __restrict__ TpB,
    const float* __restrict__ Wp, unsigned* __restrict__ minP,
    const uint4* __restrict__ TpA, const uint4* __restrict__ TgB,
    const float* __restrict__ Wg, unsigned* __restrict__ minG)
{
    __shared__ uint4 tileU[2 * SLICE * 2];   // 2 x 16 KiB A-form buffers
    char* tileC = (char*)tileU;

    const int qb = blockIdx.x, b = blockIdx.y;
    const int dir = blockIdx.z >> 1, zs = blockIdx.z & 1;
    const int t = threadIdx.x, lane = t & 63, wid = t >> 6;
    const int col = lane & 31, hi = lane >> 5;

    const uint4* TA = dir ? TpA : TgA;
    const uint4* TB = dir ? TgB : TpB;
    const float* WQ = dir ? Wg  : Wp;
    unsigned*  minb = dir ? minG : minP;

    // B fragments (round-4/6 exact addressing)
    const int qblk = qb * QB + wid * 64;
    const char* TBc = (const char*)(TB + ((size_t)b * NPTS + qblk) * 2);
    bf16x8 bq0 = *(const bf16x8*)(TBc + (size_t)col * 32 + hi * 16);
    bf16x8 bq1 = *(const bf16x8*)(TBc + (size_t)(col + 32) * 32 + hi * 16);

    f32x16 zacc;
#pragma unroll
    for (int j = 0; j < 16; ++j) zacc[j] = 0.f;
    f32x16 macc0 = zacc + 3.0e38f;
    f32x16 macc1 = macc0;
    // swizzled A-frag READ base (HW-proven since R4); tile tt at +tt*1024
    const int abase = (col * 32 + hi * 16) ^ (((col >> 2) & 7) << 4);

    // staging (R10/R11-proven): 1024 granules/stage; wave wid owns chunks
    // wid*4+it; LINEAR LDS dest + XOR-pre-swizzled global source lane.
    const uint4* TAb = TA + ((size_t)b * NPTS + (size_t)zs * HALF) * 2;
    const int swzlane = lane ^ (lane >> 3);
    const uint4* gsrc0 = TAb + wid * 256 + swzlane;
    char* ldst0 = tileC + wid * 4096;

    // prologue: stage 0 into buf0 (async; drained by barrier's vmcnt)
#pragma unroll
    for (int it = 0; it < 4; ++it)
        gload_lds16(gsrc0 + it * 64, ldst0 + it * 1024);
    __syncthreads();

    for (int st = 0; st < NSTAGE; ++st) {
        const int cur = (st & 1) * BUFB;
        if (st + 1 < NSTAGE) {               // issue next stage EARLY (async)
            const uint4* gs = gsrc0 + (size_t)(st + 1) * (SLICE * 2);
            char* ld = ldst0 + (cur ^ BUFB);
#pragma unroll
            for (int it = 0; it < 4; ++it)
                gload_lds16(gs + it * 64, ld + it * 1024);
        }

        // paired-tile loop: 2 ds_read + 4 MFMA + 2 min3x16 per iteration.
        const char* tb = tileC + cur + abase;
        bf16x8 a0 = *(const bf16x8*)(tb);
        bf16x8 a1 = *(const bf16x8*)(tb + 1024);
#pragma unroll 1
        for (int tp = 0; tp < TILES / 2; ++tp) {
            // lookahead next pair (wraps to tile 0/1 on last iter; discarded)
            const int o2 = ((2 * tp + 2) & (TILES - 1)) * 1024;
            bf16x8 n0 = *(const bf16x8*)(tb + o2);
            bf16x8 n1 = *(const bf16x8*)(tb + o2 + 1024);
            f32x16 d0e = __builtin_amdgcn_mfma_f32_32x32x16_bf16(a0, bq0, zacc, 0, 0, 0);
            f32x16 d1e = __builtin_amdgcn_mfma_f32_32x32x16_bf16(a0, bq1, zacc, 0, 0, 0);
            f32x16 d0o = __builtin_amdgcn_mfma_f32_32x32x16_bf16(a1, bq0, zacc, 0, 0, 0);
            f32x16 d1o = __builtin_amdgcn_mfma_f32_32x32x16_bf16(a1, bq1, zacc, 0, 0, 0);
            macc0 = min3x16(macc0, d0e, d0o);   // 16 v_min3: 2 distances/op
            macc1 = min3x16(macc1, d1e, d1o);
            a0 = n0; a1 = n1;
        }

        __syncthreads();                     // one barrier/stage (R8/R10 scheme)
    }

    // epilogue: 16->1 trees, combine row-halves, add ||q||^2, atomicMin
    float m0 = mintree(macc0);
    float m1 = mintree(macc1);
    m0 = fminf(m0, __shfl_xor(m0, 32));
    m1 = fminf(m1, __shfl_xor(m1, 32));
    // thread t <-> query qb*QB + t (R6-proven mapping)
    int qi = (int)((size_t)b * NPTS) + qb * QB + t;
    float wq = WQ[qi];
    float d = fmaxf((lane < 32 ? m0 : m1) + wq, 0.0f);
    atomicMin(&minb[qi], __float_as_uint(d));
}

// out += sum(a)*sc + sum(b)*sc  (multi-block; out zero-initialized)
__global__ __launch_bounds__(BLOCK) void chamfer_reduce(
    const float* __restrict__ a, const float* __restrict__ b,
    float* __restrict__ out, float sc)
{
    __shared__ float part[BLOCK / 64];
    float s = 0.f;
    int tid = blockIdx.x * BLOCK + threadIdx.x;
    int stride = gridDim.x * BLOCK;
    const float4* a4 = (const float4*)a;
    const float4* b4 = (const float4*)b;
    for (int i = tid; i < TOTAL / 4; i += stride) {
        float4 va = a4[i], vb = b4[i];
        s += (va.x + va.y + va.z + va.w) + (vb.x + vb.y + vb.z + vb.w);
    }
    s *= sc;
    for (int o = 32; o > 0; o >>= 1) s += __shfl_down(s, o, 64);
    int w = threadIdx.x >> 6;
    if ((threadIdx.x & 63) == 0) part[w] = s;
    __syncthreads();
    if (threadIdx.x == 0) {
        float tot = 0.f;
#pragma unroll
        for (int i = 0; i < BLOCK / 64; ++i) tot += part[i];
        atomicAdd(out, tot);
    }
}

extern "C" void kernel_launch(void* const* d_in, const int* in_sizes, int n_in,
                              void* d_out, int out_size, void* d_ws, size_t ws_size,
                              hipStream_t stream) {
    const float* pred = (const float*)d_in[0];   // [B, N, 3]
    const float* gt   = (const float*)d_in[1];   // [B, M, 3]
    float* out = (float*)d_out;

    // ws layout: TgA, TpA, TgB, TpB (32B/point), Wg, Wp, minP, minG
    char* ws = (char*)d_ws;
    uint4* TgA = (uint4*)(ws);
    uint4* TpA = (uint4*)(ws + (size_t)TOTAL * 32);
    uint4* TgB = (uint4*)(ws + (size_t)TOTAL * 64);
    uint4* TpB = (uint4*)(ws + (size_t)TOTAL * 96);
    float* Wg  = (float*)(ws + (size_t)TOTAL * 128);
    float* Wp  = (float*)(ws + (size_t)TOTAL * 132);
    unsigned* minP = (unsigned*)(ws + (size_t)TOTAL * 136);
    unsigned* minG = (unsigned*)(ws + (size_t)TOTAL * 140);

    hipMemsetAsync(minP, 0x7f, (size_t)TOTAL * 8, stream);  // minP+minG ~3.39e38
    hipMemsetAsync(out, 0, sizeof(float), stream);

    chamfer_prep_mfma<<<dim3(TOTAL / BLOCK, 2), BLOCK, 0, stream>>>(
        gt, pred, TgA, TgB, Wg, TpA, TpB, Wp);

    chamfer_nn_mfma<<<dim3(NPTS / QB, B_SZ, 2 * ZSPLIT), BLOCK, 0, stream>>>(
        TgA, TpB, Wp, minP, TpA, TgB, Wg, minG);

    chamfer_reduce<<<RED_GRID, BLOCK, 0, stream>>>(
        (const float*)minP, (const float*)minG, out, 1.0f / (float)TOTAL);
}